// Round 7
// baseline (361.348 us; speedup 1.0000x reference)
//
#include <hip/hip_runtime.h>
#include <hip/hip_bf16.h>

// VQ argmin via fp8(e4m3) MFMA filter + exact fp64 refine. Round 7: fix the
// cf-premin candidate-loss bug (insert all 4 cf keys into per-slot BEST-3;
// emit 3/lane-slot). Everything else identical to round 6.
// Scratch carved from d_out[0:N*D) (float offsets):
//   Xq  fp8[N][512]   @ 0        (16 MiB)
//   Cq  fp8[K][512]   @ 4194304  ( 4 MiB)
//   cand int[N][192]  @ 5242880  (24 MiB)
// c2 f32[K] in d_ws.

constexpr int NTOK = 32768, DIM = 512, KCODES = 8192;
constexpr float MARGIN = 20.0f;   // fp8 pairwise dist-err sigma ~2.3 -> ~8.7 sigma

using ffrag = __attribute__((ext_vector_type(4))) float;   // 4 f32 acc

#define GLD_LDS16(g, l)                                                        \
  __builtin_amdgcn_global_load_lds(                                            \
      (const __attribute__((address_space(1))) void*)(g),                      \
      (__attribute__((address_space(3))) void*)(l), 16, 0, 0)

// ---- f32 -> fp8 e4m3fn, explicit RNE (no HW rounding-mode ambiguity) -------
__device__ __forceinline__ unsigned char f2e4m3(float x) {
  unsigned u = __float_as_uint(x);
  unsigned s = (u >> 24) & 0x80u;
  float ax = fabsf(x);
  if (ax < 0.015625f) {                       // denormal region (< 2^-6)
    int q = (int)rintf(ax * 512.0f);          // RNE; q==8 rolls into 2^-6
    return (unsigned char)(s | (unsigned)q);
  }
  int e = (int)((u >> 23) & 0xFF) - 127;
  float m = __uint_as_float((u & 0x7FFFFFu) | 0x3F800000u);  // [1,2)
  int r = (int)rintf(m * 8.0f);               // RNE -> 8..16
  if (r == 16) { r = 8; ++e; }
  if (e > 8) { e = 8; r = 15; }               // clamp (never hit for N(0,1))
  return (unsigned char)(s | ((unsigned)(e + 7) << 3) | (unsigned)(r - 8));
}

// ---- convert fp32 rows -> fp8, optional sum-of-squares (one wave per row) --
__global__ void vq_prep8(const float* __restrict__ src, unsigned char* __restrict__ dst,
                         float* __restrict__ sq, int rows) {
  int w = (blockIdx.x * blockDim.x + threadIdx.x) >> 6;
  int lane = threadIdx.x & 63;
  if (w >= rows) return;
  const float4* r4 = (const float4*)(src + (size_t)w * DIM);
  float4 a = r4[lane * 2], b = r4[lane * 2 + 1];
  union { unsigned char c[8]; uint2 v; } o;
  o.c[0]=f2e4m3(a.x); o.c[1]=f2e4m3(a.y); o.c[2]=f2e4m3(a.z); o.c[3]=f2e4m3(a.w);
  o.c[4]=f2e4m3(b.x); o.c[5]=f2e4m3(b.y); o.c[6]=f2e4m3(b.z); o.c[7]=f2e4m3(b.w);
  *(uint2*)(dst + (size_t)w * DIM + lane * 8) = o.v;
  if (sq != nullptr) {
    float s = a.x*a.x + a.y*a.y + a.z*a.z + a.w*a.w
            + b.x*b.x + b.y*b.y + b.z*b.z + b.w*b.w;
    #pragma unroll
    for (int off = 32; off; off >>= 1) s += __shfl_down(s, off, 64);
    if (lane == 0) sq[w] = s;
  }
}

// ---- fused fp8 MFMA distance + approx best-3 + candidate emission ----------
// Block: 256 thr (4 waves: wr,wc in {0,1}), 128 rows x 4096 codes (half h).
// As: [128 rows][512] fp8, unit-swizzled (u ^= row&7). Bs: ring-4 of 4KB
// tiles, two-plane layout [v=k-half][col][16B].
__launch_bounds__(256, 2)
__global__ void vq_main(const unsigned char* __restrict__ Xq,
                        const unsigned char* __restrict__ Cq,
                        const float* __restrict__ c2g, int* __restrict__ cand) {
  __shared__ __align__(16) unsigned char As[128][512];   // 64 KiB
  __shared__ __align__(16) unsigned char Bs[4][4096];    // 16 KiB ring-4
  const int tid = threadIdx.x, lane = tid & 63;
  const int wid = tid >> 6, wr = wid >> 1, wc = wid & 1;
  const int rb = blockIdx.x & 255, h = blockIdx.x >> 8;
  const int row0 = rb * 128, ctBase = h * 32;
  const int l15 = lane & 15, l4 = lane >> 4;
  constexpr int TTB = 32 * 16;   // 512 k-tiles per block

  // ---------- prologue: As + B tiles 0,1 ----------
  #pragma unroll
  for (int it = 0; it < 16; ++it) {
    int p = it * 256 + tid, rA = p >> 5, u = p & 31;
    GLD_LDS16(Xq + (size_t)(row0 + rA) * DIM + ((u ^ (rA & 7)) << 4),
              &As[0][0] + p * 16);
  }
  {
    const int rB = tid & 127, v = tid >> 7;
    #pragma unroll
    for (int t0 = 0; t0 < 2; ++t0)
      GLD_LDS16(Cq + (size_t)(ctBase * 128 + rB) * DIM + t0 * 32 + v * 16,
                &Bs[t0][0] + tid * 16);
  }
  asm volatile("s_waitcnt vmcnt(0)" ::: "memory");
  __builtin_amdgcn_s_barrier();

  long aF[2][4], bF[2][4];
  #pragma unroll
  for (int rf = 0; rf < 4; ++rf) {    // tile-0 a-frags (kc=0)
    int rA = wr * 64 + rf * 16 + l15;
    aF[0][rf] = *(const long*)(&As[rA][0] +
                 (((l4 >> 1) ^ (rA & 7)) << 4) + ((l4 & 1) << 3));
  }
  #pragma unroll
  for (int cf = 0; cf < 4; ++cf) {    // tile-0 b-frags
    int rB = wc * 64 + cf * 16 + l15;
    bF[0][cf] = *(const long*)(&Bs[0][0] +
                 ((l4 >> 1) << 11) + (rB << 4) + ((l4 & 1) << 3));
  }

  unsigned b0k[4][4], b1k[4][4], b2k[4][4];
  #pragma unroll
  for (int rf = 0; rf < 4; ++rf)
    #pragma unroll
    for (int rg = 0; rg < 4; ++rg) {
      b0k[rf][rg] = 0xFFFFFFFFu; b1k[rf][rg] = 0xFFFFFFFFu; b2k[rf][rg] = 0xFFFFFFFFu;
    }
  ffrag acc[4][4];
  float c2v[4];

  for (int ctl = 0; ctl < 32; ++ctl) {
    #pragma unroll
    for (int kc = 0; kc < 16; ++kc) {
      const int t = ctl * 16 + kc;
      asm volatile("s_waitcnt lgkmcnt(0)" ::: "memory");
      asm volatile("s_waitcnt vmcnt(0)" ::: "memory");
      __builtin_amdgcn_s_barrier();

      // stage S(t+2) into slot (t+2)&3 (1 gld_lds / thread)
      if (t + 2 < TTB) {
        const int tt = t + 2, ctn = tt >> 4, kcn = tt & 15, sl = tt & 3;
        const int rB = tid & 127, v = tid >> 7;
        GLD_LDS16(Cq + (size_t)((ctBase + ctn) * 128 + rB) * DIM + kcn * 32 + v * 16,
                  &Bs[sl][0] + tid * 16);
      }
      if (kc == 0) {   // c2 for this ct (used at kc==15; drained by VMW(0)s)
        const int ct = ctBase + ctl;
        #pragma unroll
        for (int cf = 0; cf < 4; ++cf)
          c2v[cf] = c2g[ct * 128 + wc * 64 + cf * 16 + l15];
      }

      // frag prefetch t+1 (lands under this phase's MFMAs)
      if (t + 1 < TTB) {
        const int kcn2 = (kc + 1) & 15, pn = (kc + 1) & 1;
        const unsigned char* bsl = &Bs[(t + 1) & 3][0];
        #pragma unroll
        for (int rf = 0; rf < 4; ++rf) {
          int rA = wr * 64 + rf * 16 + l15;
          aF[pn][rf] = *(const long*)(&As[rA][0] +
                        (((kcn2 * 2 + (l4 >> 1)) ^ (rA & 7)) << 4) + ((l4 & 1) << 3));
        }
        #pragma unroll
        for (int cf = 0; cf < 4; ++cf) {
          int rB = wc * 64 + cf * 16 + l15;
          bF[pn][cf] = *(const long*)(bsl +
                        ((l4 >> 1) << 11) + (rB << 4) + ((l4 & 1) << 3));
        }
      }

      // MFMA current phase (zero-init accumulate at kc==0)
      #pragma unroll
      for (int rf = 0; rf < 4; ++rf)
        #pragma unroll
        for (int cf = 0; cf < 4; ++cf) {
          if (kc == 0) {
            ffrag z = {0.f, 0.f, 0.f, 0.f};
            acc[rf][cf] = __builtin_amdgcn_mfma_f32_16x16x32_fp8_fp8(aF[0][rf], bF[0][cf], z, 0, 0, 0);
          } else {
            acc[rf][cf] = __builtin_amdgcn_mfma_f32_16x16x32_fp8_fp8(aF[kc & 1][rf], bF[kc & 1][cf], acc[rf][cf], 0, 0, 0);
          }
        }

      if (kc == 15) {   // per-ct epilogue: insert ALL 4 cf keys into best-3
        #pragma unroll
        for (int rf = 0; rf < 4; ++rf)
          #pragma unroll
          for (int rg = 0; rg < 4; ++rg) {
            #pragma unroll
            for (int cf = 0; cf < 4; ++cf) {
              float d = fmaf(-2.0f, acc[rf][cf][rg], c2v[cf] + 2048.0f);  // key>0
              unsigned k = (__float_as_uint(d) & 0xFFFFFF00u) |
                           (unsigned)((ctl << 2) | cf);
              unsigned lo0 = min(b0k[rf][rg], k), hi0 = max(b0k[rf][rg], k);
              b0k[rf][rg] = lo0;
              unsigned lo1 = min(b1k[rf][rg], hi0), hi1 = max(b1k[rf][rg], hi0);
              b1k[rf][rg] = lo1;
              b2k[rf][rg] = min(b2k[rf][rg], hi1);
            }
          }
      }
    }  // kc
  }    // ctl

  asm volatile("s_waitcnt lgkmcnt(0)" ::: "memory");
  asm volatile("s_waitcnt vmcnt(0)" ::: "memory");
  __builtin_amdgcn_s_barrier();

  // per-row min across 16 l15-lanes; cross-wc merge via LDS (overlay on Bs)
  unsigned* dstar = (unsigned*)&Bs[0][0];   // [2][128]
  unsigned gmin[4][4];
  #pragma unroll
  for (int rf = 0; rf < 4; ++rf)
    #pragma unroll
    for (int rg = 0; rg < 4; ++rg) {
      unsigned g = b0k[rf][rg];
      #pragma unroll
      for (int m = 1; m < 16; m <<= 1)
        g = min(g, (unsigned)__shfl_xor((int)g, m, 64));
      gmin[rf][rg] = g;
      if (l15 == 0) dstar[wc * 128 + wr * 64 + rf * 16 + l4 * 4 + rg] = g;
    }
  __syncthreads();
  #pragma unroll
  for (int rf = 0; rf < 4; ++rf)
    #pragma unroll
    for (int rg = 0; rg < 4; ++rg) {
      int rl = wr * 64 + rf * 16 + l4 * 4 + rg;
      unsigned gg = min(gmin[rf][rg], dstar[(wc ^ 1) * 128 + rl]);
      float ds = __uint_as_float(gg & 0xFFFFFF00u);
      unsigned thr = __float_as_uint(ds + MARGIN);
      int base = (row0 + rl) * 192 + h * 96 + wc * 48 + l15 * 3;
      unsigned kk0 = b0k[rf][rg], kk1 = b1k[rf][rg], kk2 = b2k[rf][rg];
      int c0 = h * 4096 + (int)((kk0 >> 2) & 31u) * 128 + wc * 64 + (int)(kk0 & 3u) * 16 + l15;
      int c1 = h * 4096 + (int)((kk1 >> 2) & 31u) * 128 + wc * 64 + (int)(kk1 & 3u) * 16 + l15;
      int c2i = h * 4096 + (int)((kk2 >> 2) & 31u) * 128 + wc * 64 + (int)(kk2 & 3u) * 16 + l15;
      cand[base + 0] = (kk0 <= thr) ? c0 : -1;
      cand[base + 1] = (kk1 <= thr) ? c1 : -1;
      cand[base + 2] = (kk2 <= thr) ? c2i : -1;
    }
}

// ---- exact fp64 refine over candidate set (one wave per row, 192 slots) ----
__global__ void vq_refine(const float* __restrict__ X, const float* __restrict__ Cb,
                          const int* __restrict__ cand, float* __restrict__ idx_out) {
  int row = (blockIdx.x * blockDim.x + threadIdx.x) >> 6;
  int lane = threadIdx.x & 63;
  if (row >= NTOK) return;
  int cv0 = cand[row * 192 + lane];
  int cv1 = cand[row * 192 + 64 + lane];
  int cv2 = cand[row * 192 + 128 + lane];
  unsigned long long m0 = __ballot(cv0 >= 0);
  unsigned long long m1 = __ballot(cv1 >= 0);
  unsigned long long m2 = __ballot(cv2 >= 0);
  if (__popcll(m0) + __popcll(m1) + __popcll(m2) == 1) {
    int idx;
    if (m0)      idx = __shfl(cv0, __ffsll(m0) - 1, 64);
    else if (m1) idx = __shfl(cv1, __ffsll(m1) - 1, 64);
    else         idx = __shfl(cv2, __ffsll(m2) - 1, 64);
    if (lane == 0) idx_out[row] = (float)idx;
    return;
  }
  const float4* x4 = (const float4*)(X + (size_t)row * DIM);
  float4 xa = x4[lane * 2], xb = x4[lane * 2 + 1];
  double bestd = 1e300; int besti = 0x7FFFFFFF;
  #pragma unroll
  for (int part = 0; part < 3; ++part) {
    unsigned long long mm = part == 0 ? m0 : (part == 1 ? m1 : m2);
    int cv = part == 0 ? cv0 : (part == 1 ? cv1 : cv2);
    while (mm) {
      int src = __ffsll(mm) - 1; mm &= mm - 1;
      int idx = __shfl(cv, src, 64);
      const float4* c4 = (const float4*)(Cb + (size_t)idx * DIM);
      float4 ca = c4[lane * 2], cb = c4[lane * 2 + 1];
      double dt = (double)xa.x*ca.x + (double)xa.y*ca.y + (double)xa.z*ca.z + (double)xa.w*ca.w
                + (double)xb.x*cb.x + (double)xb.y*cb.y + (double)xb.z*cb.z + (double)xb.w*cb.w;
      double cc = (double)ca.x*ca.x + (double)ca.y*ca.y + (double)ca.z*ca.z + (double)ca.w*ca.w
                + (double)cb.x*cb.x + (double)cb.y*cb.y + (double)cb.z*cb.z + (double)cb.w*cb.w;
      double sdist = cc - 2.0 * dt;           // x2 omitted: per-row constant
      #pragma unroll
      for (int off = 32; off; off >>= 1) sdist += __shfl_down(sdist, off, 64);
      if (lane == 0 && (sdist < bestd || (sdist == bestd && idx < besti))) { bestd = sdist; besti = idx; }
    }
  }
  if (lane == 0) idx_out[row] = (float)besti;
}

// ---- final: quantized = inputs (runs LAST; overwrites scratch) -------------
__global__ void vq_copy(const float* __restrict__ in, float* __restrict__ out, int n4) {
  int i = blockIdx.x * blockDim.x + threadIdx.x;
  int st = gridDim.x * blockDim.x;
  const float4* s = (const float4*)in;
  float4* d = (float4*)out;
  for (; i < n4; i += st) d[i] = s[i];
}

extern "C" void kernel_launch(void* const* d_in, const int* in_sizes, int n_in,
                              void* d_out, int out_size, void* d_ws, size_t ws_size,
                              hipStream_t stream) {
  const float* X  = (const float*)d_in[0];
  const float* Cb = (const float*)d_in[1];
  float* out = (float*)d_out;

  unsigned char* Xq   = (unsigned char*)out;                  // [N][512] fp8
  unsigned char* Cq   = (unsigned char*)(out + 4194304);      // [K][512] fp8
  int*           cand = (int*)(out + 5242880);                // [N][192]
  float*         c2   = (float*)d_ws;                         // [K]
  float*         idx_out = out + (size_t)NTOK * DIM;

  vq_prep8<<<KCODES / 4, 256, 0, stream>>>(Cb, Cq, c2, KCODES);
  vq_prep8<<<NTOK / 4, 256, 0, stream>>>(X, Xq, nullptr, NTOK);
  vq_main<<<512, 256, 0, stream>>>(Xq, Cq, c2, cand);
  vq_refine<<<NTOK / 4, 256, 0, stream>>>(X, Cb, cand, idx_out);
  vq_copy<<<2048, 256, 0, stream>>>(X, out, NTOK * DIM / 4);
}